// Round 5
// baseline (623.274 us; speedup 1.0000x reference)
//
#include <hip/hip_runtime.h>
#include <cstdint>
#include <cstddef>

#define NB2 2048            // duration buckets (uniform [0,1))
#define NB2P 2049           // padded per-cause stride (breaks LDS bank aliasing)
#define NCELLP (NB2P * 4)   // 8196 cells per private histogram
#define CEPAD 44            // padded floats per staged logits row (16B-aligned)
#define ALPHA 0.4
#define EPS 1e-8

// Workspace layout:
//   [0,128)    double acc[9]: [0..3] sum eta/cause, [4..7] sum log(denom)/cause, [8] CE sum
//   [128,144)  uint cnt[4]
//   [160,164)  uint done (pass3 last-block ticket)
//   [4096, +nparts*NCELLP*4)  float partial[nparts][NCELLP]  (SoA, padded)
//   then       float histAoS[NB2*4]  (AoS: [b*4+c])
//   then       float suffix[NB2*4]   (AoS)

// ---- Hazard kernel: 8 lanes/sample butterfly, 2x-unrolled sweep, LDS hist ----
__global__ __launch_bounds__(256) void hazard_kernel(
    const float4* __restrict__ log_h4, const float* __restrict__ dur,
    const int* __restrict__ ev, float* __restrict__ partial,
    double* __restrict__ acc, unsigned int* __restrict__ cnt, int N)
{
  __shared__ __align__(16) float h[NCELLP];
  __shared__ float s_f[4];
  __shared__ unsigned int s_u[4];
  const int t = threadIdx.x;
  for (int j = t; j < NCELLP; j += 256) h[j] = 0.f;
  if (t < 4) { s_f[t] = 0.f; s_u[t] = 0u; }
  __syncthreads();

  const int lane = t & 63;
  const int m = lane & 7;              // head index within group
  const int g = lane >> 3;             // sample group 0..7 within wave
  const int wv = blockIdx.x * 4 + (t >> 6);
  const int sweep = gridDim.x * 4 * 8; // samples per sweep step

  float ea = 0.f;
  unsigned ec = 0u;

  for (int s0 = wv * 8; s0 < N; s0 += 2 * sweep) {
    const int sa = s0 + g;
    const int sb = s0 + sweep + g;
    float4 va = make_float4(0.f, 0.f, 0.f, 0.f);
    float4 vb = va;
    if (sa < N) va = log_h4[(size_t)sa * 8 + m];   // lane-contiguous: coalesced
    if (sb < N) vb = log_h4[(size_t)sb * 8 + m];   // second load in flight
#pragma unroll
    for (int off = 1; off <= 4; off <<= 1) {       // butterfly over 8 heads
      va.x += __shfl_xor(va.x, off); va.y += __shfl_xor(va.y, off);
      va.z += __shfl_xor(va.z, off); va.w += __shfl_xor(va.w, off);
      vb.x += __shfl_xor(vb.x, off); vb.y += __shfl_xor(vb.y, off);
      vb.z += __shfl_xor(vb.z, off); vb.w += __shfl_xor(vb.w, off);
    }
    if (m < 4) {                       // lane m handles cause m for its sample
      if (sa < N) {
        float sc = (m == 0) ? va.x : (m == 1) ? va.y : (m == 2) ? va.z : va.w;
        float eta = fminf(fmaxf(sc * 0.125f, -50.f), 50.f);
        int b = (int)(dur[sa] * (float)NB2);
        b = b < 0 ? 0 : (b > NB2 - 1 ? NB2 - 1 : b);
        atomicAdd(&h[m * NB2P + b], __expf(eta));
        if (ev[sa] == m + 1) { ea += eta; ec += 1u; }
      }
      if (sb < N) {
        float sc = (m == 0) ? vb.x : (m == 1) ? vb.y : (m == 2) ? vb.z : vb.w;
        float eta = fminf(fmaxf(sc * 0.125f, -50.f), 50.f);
        int b = (int)(dur[sb] * (float)NB2);
        b = b < 0 ? 0 : (b > NB2 - 1 ? NB2 - 1 : b);
        atomicAdd(&h[m * NB2P + b], __expf(eta));
        if (ev[sb] == m + 1) { ea += eta; ec += 1u; }
      }
    }
  }
#pragma unroll
  for (int off = 8; off <= 32; off <<= 1) {   // fold groups, preserving m
    ea += __shfl_down(ea, off);
    ec += __shfl_down(ec, off);
  }
  if (lane < 4) { atomicAdd(&s_f[lane], ea); atomicAdd(&s_u[lane], ec); }
  __syncthreads();

  float4* outp = (float4*)(partial + (size_t)blockIdx.x * NCELLP);
  const float4* h4p = (const float4*)h;
  for (int j = t; j < NCELLP / 4; j += 256) outp[j] = h4p[j];
  if (t < 4) {
    unsafeAtomicAdd(&acc[t], (double)s_f[t]);
    atomicAdd(&cnt[t], s_u[t]);
  }
}

// ---- CE kernel: LDS-staged tiles, coalesced float4 global loads ----
__global__ __launch_bounds__(256) void ce_kernel(
    const float4* __restrict__ logits4, const int* __restrict__ lab,
    double* __restrict__ acc, int N)
{
  __shared__ __align__(16) float sL[256 * CEPAD];   // 45 KB -> 3 blocks/CU
  const int t = threadIdx.x;
  float ce = 0.f;
  const int nTiles = (N + 255) / 256;
  for (int tile = blockIdx.x; tile < nTiles; tile += gridDim.x) {
    const int base = tile * 256;
    const int tileN = min(256, N - base);
    __syncthreads();                   // protect sL from previous iteration
    if (tileN == 256) {                // fast path: unguarded, 10 loads in flight
      float4 v[10];
#pragma unroll
      for (int j = 0; j < 10; ++j) v[j] = logits4[(size_t)base * 10 + j * 256 + t];
#pragma unroll
      for (int j = 0; j < 10; ++j) {
        int gidx = j * 256 + t;
        int row = gidx / 10, cc = gidx - row * 10;
        *(float4*)&sL[row * CEPAD + cc * 4] = v[j];
      }
    } else {
      const int nChunk = tileN * 10;
#pragma unroll
      for (int j = 0; j < 10; ++j) {
        int gidx = j * 256 + t;
        if (gidx < nChunk) {
          float4 v = logits4[(size_t)base * 10 + gidx];
          int row = gidx / 10, cc = gidx - row * 10;
          *(float4*)&sL[row * CEPAD + cc * 4] = v;
        }
      }
    }
    __syncthreads();
    if (t < tileN) {
      const float4* r = (const float4*)&sL[t * CEPAD];
      float x[40];
#pragma unroll
      for (int j = 0; j < 10; ++j) ((float4*)x)[j] = r[j];
      float L0 = 0.f, L1 = 0.f, L2 = 0.f, L3 = 0.f, L4 = 0.f;
#pragma unroll
      for (int mm = 0; mm < 8; ++mm) {
        L0 += x[mm * 5 + 0]; L1 += x[mm * 5 + 1]; L2 += x[mm * 5 + 2];
        L3 += x[mm * 5 + 3]; L4 += x[mm * 5 + 4];
      }
      L0 *= 0.125f; L1 *= 0.125f; L2 *= 0.125f; L3 *= 0.125f; L4 *= 0.125f;
      float mx = fmaxf(fmaxf(fmaxf(L0, L1), fmaxf(L2, L3)), L4);
      float se = __expf(L0 - mx) + __expf(L1 - mx) + __expf(L2 - mx) +
                 __expf(L3 - mx) + __expf(L4 - mx);
      float lse = __logf(se) + mx;
      int lb = lab[base + t];
      float lsel = (lb == 0) ? L0 : (lb == 1) ? L1 : (lb == 2) ? L2
                 : (lb == 3) ? L3 : L4;
      ce += lsel - lse;
    }
  }
  for (int o = 32; o; o >>= 1) ce += __shfl_down(ce, o);
  __shared__ float s_ce;
  if (t == 0) s_ce = 0.f;
  __syncthreads();
  if ((t & 63) == 0) atomicAdd(&s_ce, ce);
  __syncthreads();
  if (t == 0) unsafeAtomicAdd(&acc[8], (double)s_ce);
}

// Fold nparts padded partial histograms into one AoS histogram.
__global__ __launch_bounds__(256) void reduce_kernel(
    const float* __restrict__ partial, float* __restrict__ histAoS, int nparts)
{
  const int c  = blockIdx.x >> 6;
  const int bg = blockIdx.x & 63;
  const int tc = threadIdx.x & 31;
  const int tp = threadIdx.x >> 5;
  const int b = bg * 32 + tc;
  const int cell = c * NB2P + b;
  float s = 0.f;
  for (int p = tp; p < nparts; p += 8)
    s += partial[(size_t)p * NCELLP + cell];
  __shared__ float sh[256];
  sh[threadIdx.x] = s;
  __syncthreads();
  if (threadIdx.x < 32) {
    float v = 0.f;
#pragma unroll
    for (int k = 0; k < 8; ++k) v += sh[k * 32 + tc];
    histAoS[b * 4 + c] = v;
  }
}

// Inclusive suffix-sum over NB2 buckets (float4 = 4 causes). One WG.
__global__ __launch_bounds__(1024) void scan_kernel(
    const float* __restrict__ hist, float* __restrict__ suffix)
{
  const int CH = NB2 / 1024;   // 2
  const int t = threadIdx.x;
  __shared__ float4 part[1024];
  const float4* in = (const float4*)hist;
  float4* out = (float4*)suffix;

  float4 a = make_float4(0.f, 0.f, 0.f, 0.f);
  for (int j = 0; j < CH; ++j) {
    float4 v = in[t * CH + j];
    a.x += v.x; a.y += v.y; a.z += v.z; a.w += v.w;
  }
  part[t] = a;
  __syncthreads();
  for (int off = 1; off < 1024; off <<= 1) {
    float4 add = make_float4(0.f, 0.f, 0.f, 0.f);
    if (t + off < 1024) add = part[t + off];
    __syncthreads();
    float4 cur = part[t];
    cur.x += add.x; cur.y += add.y; cur.z += add.z; cur.w += add.w;
    part[t] = cur;
    __syncthreads();
  }
  float4 carry = (t < 1023) ? part[t + 1] : make_float4(0.f, 0.f, 0.f, 0.f);
  for (int j = CH - 1; j >= 0; --j) {
    float4 v = in[t * CH + j];
    carry.x += v.x; carry.y += v.y; carry.z += v.z; carry.w += v.w;
    out[t * CH + j] = carry;
  }
}

// ---- pass3 + fused finalize (last-block ticket; all shared state via atomics) ----
__global__ __launch_bounds__(256) void pass3_kernel(
    const float* __restrict__ dur, const int* __restrict__ ev,
    const float* __restrict__ suffix, double* __restrict__ acc,
    unsigned int* __restrict__ cnt, unsigned int* __restrict__ done,
    float* __restrict__ out, int N, int nblocks)
{
  const int t = threadIdx.x;
  float lg0 = 0.f, lg1 = 0.f, lg2 = 0.f, lg3 = 0.f;
  const int i = blockIdx.x * 256 + t;
  if (i < N) {
    int e = ev[i];
    if (e > 0) {
      int b = (int)(dur[i] * (float)NB2);
      b = b < 0 ? 0 : (b > NB2 - 1 ? NB2 - 1 : b);
      float lv = __logf(suffix[(size_t)b * 4 + (e - 1)] + (float)EPS);
      lg0 = (e == 1) ? lv : 0.f;
      lg1 = (e == 2) ? lv : 0.f;
      lg2 = (e == 3) ? lv : 0.f;
      lg3 = (e == 4) ? lv : 0.f;
    }
  }
#define WRED(v) { for (int o = 32; o; o >>= 1) v += __shfl_down(v, o); }
  WRED(lg0) WRED(lg1) WRED(lg2) WRED(lg3)
  __shared__ float s_lg[4];
  if (t < 4) s_lg[t] = 0.f;
  __syncthreads();
  if ((t & 63) == 0) {
    atomicAdd(&s_lg[0], lg0); atomicAdd(&s_lg[1], lg1);
    atomicAdd(&s_lg[2], lg2); atomicAdd(&s_lg[3], lg3);
  }
  __syncthreads();
  if (t < 4 && s_lg[t] != 0.f) unsafeAtomicAdd(&acc[4 + t], (double)s_lg[t]);

  // last-block finalize: acc/cnt are only ever touched by device-scope atomics
  __shared__ bool last;
  __threadfence();
  if (t == 0) last = (atomicAdd(done, 1u) == (unsigned)(nblocks - 1));
  __syncthreads();
  if (last && t == 0) {
    __threadfence();
    double ls = 0.0;
    for (int c = 0; c < 4; ++c) {
      double se = unsafeAtomicAdd(&acc[c], 0.0);       // coherent atomic read
      double sl = unsafeAtomicAdd(&acc[4 + c], 0.0);
      unsigned cc = atomicAdd(&cnt[c], 0u);
      ls += -(se - sl) / ((double)cc + EPS);
    }
    double ce = -unsafeAtomicAdd(&acc[8], 0.0) / (double)N;
    out[0] = (float)(ALPHA * ls + (1.0 - ALPHA) * ce);
  }
}

extern "C" void kernel_launch(void* const* d_in, const int* in_sizes, int n_in,
                              void* d_out, int out_size, void* d_ws, size_t ws_size,
                              hipStream_t stream) {
  const float4* log_h4  = (const float4*)d_in[0];
  const float4* logits4 = (const float4*)d_in[1];
  const float*  dur     = (const float*)d_in[2];
  const int*    ev      = (const int*)d_in[3];
  const int*    lab     = (const int*)d_in[4];
  const int N = in_sizes[2];

  const size_t partBytes = (size_t)NCELLP * sizeof(float);   // 32784 B
  const size_t histBytes = (size_t)NB2 * 4 * sizeof(float);  // 32 KB
  size_t fixed = 4096 + 2 * histBytes;
  int nparts = 512;                      // 2 blocks/CU; halves partial traffic
  if (ws_size > fixed) {
    size_t fit = (ws_size - fixed) / partBytes;
    if ((size_t)nparts > fit) nparts = (int)fit;
  }
  if (nparts < 1) nparts = 1;

  char* ws = (char*)d_ws;
  double* acc = (double*)ws;
  unsigned int* cnt = (unsigned int*)(ws + 128);
  unsigned int* done = (unsigned int*)(ws + 160);
  float* partial = (float*)(ws + 4096);
  float* histAoS = (float*)(ws + 4096 + (size_t)nparts * partBytes);
  float* suffix  = (float*)(ws + 4096 + (size_t)nparts * partBytes + histBytes);

  hipMemsetAsync(ws, 0, 4096, stream);    // header only; all else fully written

  hazard_kernel<<<nparts, 256, 0, stream>>>(log_h4, dur, ev, partial, acc, cnt, N);
  ce_kernel<<<768, 256, 0, stream>>>(logits4, lab, acc, N);
  reduce_kernel<<<256, 256, 0, stream>>>(partial, histAoS, nparts);
  scan_kernel<<<1, 1024, 0, stream>>>(histAoS, suffix);
  const int nb = (N + 255) / 256;
  pass3_kernel<<<nb, 256, 0, stream>>>(dur, ev, suffix, acc, cnt, done,
                                       (float*)d_out, N, nb);
}

// Round 6
// 443.919 us; speedup vs baseline: 1.4040x; 1.4040x over previous
//
#include <hip/hip_runtime.h>
#include <cstdint>
#include <cstddef>

#define NB2 2048            // duration buckets (uniform [0,1))
#define NB2P 2049           // padded per-cause stride (breaks LDS bank aliasing)
#define NCELLP (NB2P * 4)   // 8196 cells per private histogram
#define CEPAD 44            // padded floats per staged logits row (16B-aligned)
#define ALPHA 0.4
#define EPS 1e-8

// Workspace layout:
//   [0,128)    double acc[9]: [0..3] sum eta/cause, [4..7] sum log(denom)/cause, [8] CE sum
//   [128,144)  uint cnt[4]
//   [4096, +nparts*NCELLP*4)  float partial[nparts][NCELLP]  (SoA, padded)
//   then       float histAoS[NB2*4]  (AoS: [b*4+c])
//   then       float suffix[NB2*4]   (AoS)

// ---- Hazard kernel: 8 lanes/sample butterfly, 2x-unrolled sweep, LDS hist ----
__global__ __launch_bounds__(256) void hazard_kernel(
    const float4* __restrict__ log_h4, const float* __restrict__ dur,
    const int* __restrict__ ev, float* __restrict__ partial,
    double* __restrict__ acc, unsigned int* __restrict__ cnt, int N)
{
  __shared__ __align__(16) float h[NCELLP];
  __shared__ float s_f[4];
  __shared__ unsigned int s_u[4];
  const int t = threadIdx.x;
  for (int j = t; j < NCELLP; j += 256) h[j] = 0.f;
  if (t < 4) { s_f[t] = 0.f; s_u[t] = 0u; }
  __syncthreads();

  const int lane = t & 63;
  const int m = lane & 7;              // head index within group
  const int g = lane >> 3;             // sample group 0..7 within wave
  const int wv = blockIdx.x * 4 + (t >> 6);
  const int sweep = gridDim.x * 4 * 8; // samples per sweep step

  float ea = 0.f;
  unsigned ec = 0u;

  for (int s0 = wv * 8; s0 < N; s0 += 2 * sweep) {
    const int sa = s0 + g;
    const int sb = s0 + sweep + g;
    float4 va = make_float4(0.f, 0.f, 0.f, 0.f);
    float4 vb = va;
    if (sa < N) va = log_h4[(size_t)sa * 8 + m];   // lane-contiguous: coalesced
    if (sb < N) vb = log_h4[(size_t)sb * 8 + m];   // second load in flight
#pragma unroll
    for (int off = 1; off <= 4; off <<= 1) {       // butterfly over 8 heads
      va.x += __shfl_xor(va.x, off); va.y += __shfl_xor(va.y, off);
      va.z += __shfl_xor(va.z, off); va.w += __shfl_xor(va.w, off);
      vb.x += __shfl_xor(vb.x, off); vb.y += __shfl_xor(vb.y, off);
      vb.z += __shfl_xor(vb.z, off); vb.w += __shfl_xor(vb.w, off);
    }
    if (m < 4) {                       // lane m handles cause m for its sample
      if (sa < N) {
        float sc = (m == 0) ? va.x : (m == 1) ? va.y : (m == 2) ? va.z : va.w;
        float eta = fminf(fmaxf(sc * 0.125f, -50.f), 50.f);
        int b = (int)(dur[sa] * (float)NB2);
        b = b < 0 ? 0 : (b > NB2 - 1 ? NB2 - 1 : b);
        atomicAdd(&h[m * NB2P + b], __expf(eta));
        if (ev[sa] == m + 1) { ea += eta; ec += 1u; }
      }
      if (sb < N) {
        float sc = (m == 0) ? vb.x : (m == 1) ? vb.y : (m == 2) ? vb.z : vb.w;
        float eta = fminf(fmaxf(sc * 0.125f, -50.f), 50.f);
        int b = (int)(dur[sb] * (float)NB2);
        b = b < 0 ? 0 : (b > NB2 - 1 ? NB2 - 1 : b);
        atomicAdd(&h[m * NB2P + b], __expf(eta));
        if (ev[sb] == m + 1) { ea += eta; ec += 1u; }
      }
    }
  }
#pragma unroll
  for (int off = 8; off <= 32; off <<= 1) {   // fold groups, preserving m
    ea += __shfl_down(ea, off);
    ec += __shfl_down(ec, off);
  }
  if (lane < 4) { atomicAdd(&s_f[lane], ea); atomicAdd(&s_u[lane], ec); }
  __syncthreads();

  float4* outp = (float4*)(partial + (size_t)blockIdx.x * NCELLP);
  const float4* h4p = (const float4*)h;
  for (int j = t; j < NCELLP / 4; j += 256) outp[j] = h4p[j];
  if (t < 4) {
    unsafeAtomicAdd(&acc[t], (double)s_f[t]);
    atomicAdd(&cnt[t], s_u[t]);
  }
}

// ---- CE kernel: LDS-staged tiles, coalesced float4 global loads ----
__global__ __launch_bounds__(256) void ce_kernel(
    const float4* __restrict__ logits4, const int* __restrict__ lab,
    double* __restrict__ acc, int N)
{
  __shared__ __align__(16) float sL[256 * CEPAD];   // 45 KB -> 3 blocks/CU
  const int t = threadIdx.x;
  float ce = 0.f;
  const int nTiles = (N + 255) / 256;
  for (int tile = blockIdx.x; tile < nTiles; tile += gridDim.x) {
    const int base = tile * 256;
    const int tileN = min(256, N - base);
    __syncthreads();                   // protect sL from previous iteration
    if (tileN == 256) {                // fast path: unguarded, 10 loads in flight
      float4 v[10];
#pragma unroll
      for (int j = 0; j < 10; ++j) v[j] = logits4[(size_t)base * 10 + j * 256 + t];
#pragma unroll
      for (int j = 0; j < 10; ++j) {
        int gidx = j * 256 + t;
        int row = gidx / 10, cc = gidx - row * 10;
        *(float4*)&sL[row * CEPAD + cc * 4] = v[j];
      }
    } else {
      const int nChunk = tileN * 10;
#pragma unroll
      for (int j = 0; j < 10; ++j) {
        int gidx = j * 256 + t;
        if (gidx < nChunk) {
          float4 v = logits4[(size_t)base * 10 + gidx];
          int row = gidx / 10, cc = gidx - row * 10;
          *(float4*)&sL[row * CEPAD + cc * 4] = v;
        }
      }
    }
    __syncthreads();
    if (t < tileN) {
      const float4* r = (const float4*)&sL[t * CEPAD];
      float x[40];
#pragma unroll
      for (int j = 0; j < 10; ++j) ((float4*)x)[j] = r[j];
      float L0 = 0.f, L1 = 0.f, L2 = 0.f, L3 = 0.f, L4 = 0.f;
#pragma unroll
      for (int mm = 0; mm < 8; ++mm) {
        L0 += x[mm * 5 + 0]; L1 += x[mm * 5 + 1]; L2 += x[mm * 5 + 2];
        L3 += x[mm * 5 + 3]; L4 += x[mm * 5 + 4];
      }
      L0 *= 0.125f; L1 *= 0.125f; L2 *= 0.125f; L3 *= 0.125f; L4 *= 0.125f;
      float mx = fmaxf(fmaxf(fmaxf(L0, L1), fmaxf(L2, L3)), L4);
      float se = __expf(L0 - mx) + __expf(L1 - mx) + __expf(L2 - mx) +
                 __expf(L3 - mx) + __expf(L4 - mx);
      float lse = __logf(se) + mx;
      int lb = lab[base + t];
      float lsel = (lb == 0) ? L0 : (lb == 1) ? L1 : (lb == 2) ? L2
                 : (lb == 3) ? L3 : L4;
      ce += lsel - lse;
    }
  }
  for (int o = 32; o; o >>= 1) ce += __shfl_down(ce, o);
  __shared__ float s_ce;
  if (t == 0) s_ce = 0.f;
  __syncthreads();
  if ((t & 63) == 0) atomicAdd(&s_ce, ce);
  __syncthreads();
  if (t == 0) unsafeAtomicAdd(&acc[8], (double)s_ce);
}

// Fold nparts padded partial histograms into one AoS histogram.
__global__ __launch_bounds__(256) void reduce_kernel(
    const float* __restrict__ partial, float* __restrict__ histAoS, int nparts)
{
  const int c  = blockIdx.x >> 6;
  const int bg = blockIdx.x & 63;
  const int tc = threadIdx.x & 31;
  const int tp = threadIdx.x >> 5;
  const int b = bg * 32 + tc;
  const int cell = c * NB2P + b;
  float s = 0.f;
  for (int p = tp; p < nparts; p += 8)
    s += partial[(size_t)p * NCELLP + cell];
  __shared__ float sh[256];
  sh[threadIdx.x] = s;
  __syncthreads();
  if (threadIdx.x < 32) {
    float v = 0.f;
#pragma unroll
    for (int k = 0; k < 8; ++k) v += sh[k * 32 + tc];
    histAoS[b * 4 + c] = v;
  }
}

// Inclusive suffix-sum over NB2 buckets (float4 = 4 causes). One WG.
__global__ __launch_bounds__(1024) void scan_kernel(
    const float* __restrict__ hist, float* __restrict__ suffix)
{
  const int CH = NB2 / 1024;   // 2
  const int t = threadIdx.x;
  __shared__ float4 part[1024];
  const float4* in = (const float4*)hist;
  float4* out = (float4*)suffix;

  float4 a = make_float4(0.f, 0.f, 0.f, 0.f);
  for (int j = 0; j < CH; ++j) {
    float4 v = in[t * CH + j];
    a.x += v.x; a.y += v.y; a.z += v.z; a.w += v.w;
  }
  part[t] = a;
  __syncthreads();
  for (int off = 1; off < 1024; off <<= 1) {
    float4 add = make_float4(0.f, 0.f, 0.f, 0.f);
    if (t + off < 1024) add = part[t + off];
    __syncthreads();
    float4 cur = part[t];
    cur.x += add.x; cur.y += add.y; cur.z += add.z; cur.w += add.w;
    part[t] = cur;
    __syncthreads();
  }
  float4 carry = (t < 1023) ? part[t + 1] : make_float4(0.f, 0.f, 0.f, 0.f);
  for (int j = CH - 1; j >= 0; --j) {
    float4 v = in[t * CH + j];
    carry.x += v.x; carry.y += v.y; carry.z += v.z; carry.w += v.w;
    out[t * CH + j] = carry;
  }
}

// ---- pass3: pure reduction, no fence/ticket (fused finalize cost 228 us in R5) ----
__global__ __launch_bounds__(256) void pass3_kernel(
    const float* __restrict__ dur, const int* __restrict__ ev,
    const float* __restrict__ suffix, double* __restrict__ acc, int N)
{
  const int t = threadIdx.x;
  float lg0 = 0.f, lg1 = 0.f, lg2 = 0.f, lg3 = 0.f;
  const int i = blockIdx.x * 256 + t;
  if (i < N) {
    int e = ev[i];
    if (e > 0) {
      int b = (int)(dur[i] * (float)NB2);
      b = b < 0 ? 0 : (b > NB2 - 1 ? NB2 - 1 : b);
      float lv = __logf(suffix[(size_t)b * 4 + (e - 1)] + (float)EPS);
      lg0 = (e == 1) ? lv : 0.f;
      lg1 = (e == 2) ? lv : 0.f;
      lg2 = (e == 3) ? lv : 0.f;
      lg3 = (e == 4) ? lv : 0.f;
    }
  }
#define WRED(v) { for (int o = 32; o; o >>= 1) v += __shfl_down(v, o); }
  WRED(lg0) WRED(lg1) WRED(lg2) WRED(lg3)
  __shared__ float s_lg[4];
  if (t < 4) s_lg[t] = 0.f;
  __syncthreads();
  if ((t & 63) == 0) {
    atomicAdd(&s_lg[0], lg0); atomicAdd(&s_lg[1], lg1);
    atomicAdd(&s_lg[2], lg2); atomicAdd(&s_lg[3], lg3);
  }
  __syncthreads();
  if (t < 4 && s_lg[t] != 0.f) unsafeAtomicAdd(&acc[4 + t], (double)s_lg[t]);
}

__global__ void finalize_kernel(const double* __restrict__ acc,
                                const unsigned int* __restrict__ cnt,
                                float* __restrict__ out, int N)
{
  if (threadIdx.x == 0 && blockIdx.x == 0) {
    double ls = 0.0;
    for (int c = 0; c < 4; ++c) {
      double s = acc[c] - acc[4 + c];
      ls += -s / ((double)cnt[c] + EPS);
    }
    double ce = -acc[8] / (double)N;
    out[0] = (float)(ALPHA * ls + (1.0 - ALPHA) * ce);
  }
}

extern "C" void kernel_launch(void* const* d_in, const int* in_sizes, int n_in,
                              void* d_out, int out_size, void* d_ws, size_t ws_size,
                              hipStream_t stream) {
  const float4* log_h4  = (const float4*)d_in[0];
  const float4* logits4 = (const float4*)d_in[1];
  const float*  dur     = (const float*)d_in[2];
  const int*    ev      = (const int*)d_in[3];
  const int*    lab     = (const int*)d_in[4];
  const int N = in_sizes[2];

  const size_t partBytes = (size_t)NCELLP * sizeof(float);   // 32784 B
  const size_t histBytes = (size_t)NB2 * 4 * sizeof(float);  // 32 KB
  size_t fixed = 4096 + 2 * histBytes;
  int nparts = 512;                      // 2 blocks/CU; halves partial traffic
  if (ws_size > fixed) {
    size_t fit = (ws_size - fixed) / partBytes;
    if ((size_t)nparts > fit) nparts = (int)fit;
  }
  if (nparts < 1) nparts = 1;

  char* ws = (char*)d_ws;
  double* acc = (double*)ws;
  unsigned int* cnt = (unsigned int*)(ws + 128);
  float* partial = (float*)(ws + 4096);
  float* histAoS = (float*)(ws + 4096 + (size_t)nparts * partBytes);
  float* suffix  = (float*)(ws + 4096 + (size_t)nparts * partBytes + histBytes);

  hipMemsetAsync(ws, 0, 4096, stream);    // header only; all else fully written

  hazard_kernel<<<nparts, 256, 0, stream>>>(log_h4, dur, ev, partial, acc, cnt, N);
  ce_kernel<<<768, 256, 0, stream>>>(logits4, lab, acc, N);
  reduce_kernel<<<256, 256, 0, stream>>>(partial, histAoS, nparts);
  scan_kernel<<<1, 1024, 0, stream>>>(histAoS, suffix);
  const int nb = (N + 255) / 256;
  pass3_kernel<<<nb, 256, 0, stream>>>(dur, ev, suffix, acc, N);
  finalize_kernel<<<1, 1, 0, stream>>>(acc, cnt, (float*)d_out, N);
}

// Round 7
// 423.671 us; speedup vs baseline: 1.4711x; 1.0478x over previous
//
#include <hip/hip_runtime.h>
#include <cstdint>
#include <cstddef>

#define NB2 2048            // duration buckets (uniform [0,1))
#define NB2P 2049           // padded per-cause stride (breaks LDS bank aliasing)
#define NCELLP (NB2P * 4)   // 8196 cells per private histogram
#define CEPAD 44            // padded floats per staged logits row (16B-aligned)
#define ALPHA 0.4
#define EPS 1e-8

// Workspace layout:
//   [0,128)    double acc[9]: [0..3] sum eta/cause, [4..7] sum log(denom)/cause, [8] CE sum
//   [128,144)  uint cnt[4]
//   [4096, +nparts*NCELLP*4)  float partial[nparts][NCELLP]  (SoA, padded)
//   then       float histAoS[NB2*4]  (AoS: [b*4+c])
//   then       float suffix[NB2*4]   (AoS)

// ---- Hazard kernel: 8 lanes/sample butterfly, 2x-unrolled sweep, LDS hist ----
// nparts=1024 (4 blocks/CU, 16 waves/CU): R5's 512 regressed 107us vs R4 <94us
// -> latency-bound, wants TLP. dur/ev loads hoisted above the shuffle chain.
__global__ __launch_bounds__(256) void hazard_kernel(
    const float4* __restrict__ log_h4, const float* __restrict__ dur,
    const int* __restrict__ ev, float* __restrict__ partial,
    double* __restrict__ acc, unsigned int* __restrict__ cnt, int N)
{
  __shared__ __align__(16) float h[NCELLP];
  __shared__ float s_f[4];
  __shared__ unsigned int s_u[4];
  const int t = threadIdx.x;
  for (int j = t; j < NCELLP; j += 256) h[j] = 0.f;
  if (t < 4) { s_f[t] = 0.f; s_u[t] = 0u; }
  __syncthreads();

  const int lane = t & 63;
  const int m = lane & 7;              // head index within group
  const int g = lane >> 3;             // sample group 0..7 within wave
  const int wv = blockIdx.x * 4 + (t >> 6);
  const int sweep = gridDim.x * 4 * 8; // samples per sweep step

  float ea = 0.f;
  unsigned ec = 0u;

  for (int s0 = wv * 8; s0 < N; s0 += 2 * sweep) {
    const int sa = s0 + g;
    const int sb = s0 + sweep + g;
    float4 va = make_float4(0.f, 0.f, 0.f, 0.f);
    float4 vb = va;
    // issue ALL global loads first so their latency overlaps the shuffles
    if (sa < N) va = log_h4[(size_t)sa * 8 + m];   // lane-contiguous: coalesced
    float da = (sa < N) ? dur[sa] : 0.f;           // 8 words/wave, same lines
    int   eA = (sa < N) ? ev[sa] : 0;
    if (sb < N) vb = log_h4[(size_t)sb * 8 + m];
    float db = (sb < N) ? dur[sb] : 0.f;
    int   eB = (sb < N) ? ev[sb] : 0;
#pragma unroll
    for (int off = 1; off <= 4; off <<= 1) {       // butterfly over 8 heads
      va.x += __shfl_xor(va.x, off); va.y += __shfl_xor(va.y, off);
      va.z += __shfl_xor(va.z, off); va.w += __shfl_xor(va.w, off);
      vb.x += __shfl_xor(vb.x, off); vb.y += __shfl_xor(vb.y, off);
      vb.z += __shfl_xor(vb.z, off); vb.w += __shfl_xor(vb.w, off);
    }
    if (m < 4) {                       // lane m handles cause m for its sample
      if (sa < N) {
        float sc = (m == 0) ? va.x : (m == 1) ? va.y : (m == 2) ? va.z : va.w;
        float eta = fminf(fmaxf(sc * 0.125f, -50.f), 50.f);
        int b = (int)(da * (float)NB2);
        b = b < 0 ? 0 : (b > NB2 - 1 ? NB2 - 1 : b);
        atomicAdd(&h[m * NB2P + b], __expf(eta));
        if (eA == m + 1) { ea += eta; ec += 1u; }
      }
      if (sb < N) {
        float sc = (m == 0) ? vb.x : (m == 1) ? vb.y : (m == 2) ? vb.z : vb.w;
        float eta = fminf(fmaxf(sc * 0.125f, -50.f), 50.f);
        int b = (int)(db * (float)NB2);
        b = b < 0 ? 0 : (b > NB2 - 1 ? NB2 - 1 : b);
        atomicAdd(&h[m * NB2P + b], __expf(eta));
        if (eB == m + 1) { ea += eta; ec += 1u; }
      }
    }
  }
#pragma unroll
  for (int off = 8; off <= 32; off <<= 1) {   // fold groups, preserving m
    ea += __shfl_down(ea, off);
    ec += __shfl_down(ec, off);
  }
  if (lane < 4) { atomicAdd(&s_f[lane], ea); atomicAdd(&s_u[lane], ec); }
  __syncthreads();

  float4* outp = (float4*)(partial + (size_t)blockIdx.x * NCELLP);
  const float4* h4p = (const float4*)h;
  for (int j = t; j < NCELLP / 4; j += 256) outp[j] = h4p[j];
  if (t < 4) {
    unsafeAtomicAdd(&acc[t], (double)s_f[t]);
    atomicAdd(&cnt[t], s_u[t]);
  }
}

// ---- CE kernel: LDS-staged tiles, coalesced float4 global loads ----
__global__ __launch_bounds__(256) void ce_kernel(
    const float4* __restrict__ logits4, const int* __restrict__ lab,
    double* __restrict__ acc, int N)
{
  __shared__ __align__(16) float sL[256 * CEPAD];   // 45 KB -> 3 blocks/CU
  const int t = threadIdx.x;
  float ce = 0.f;
  const int nTiles = (N + 255) / 256;
  for (int tile = blockIdx.x; tile < nTiles; tile += gridDim.x) {
    const int base = tile * 256;
    const int tileN = min(256, N - base);
    __syncthreads();                   // protect sL from previous iteration
    if (tileN == 256) {                // fast path: unguarded, 10 loads in flight
      float4 v[10];
#pragma unroll
      for (int j = 0; j < 10; ++j) v[j] = logits4[(size_t)base * 10 + j * 256 + t];
#pragma unroll
      for (int j = 0; j < 10; ++j) {
        int gidx = j * 256 + t;
        int row = gidx / 10, cc = gidx - row * 10;
        *(float4*)&sL[row * CEPAD + cc * 4] = v[j];
      }
    } else {
      const int nChunk = tileN * 10;
#pragma unroll
      for (int j = 0; j < 10; ++j) {
        int gidx = j * 256 + t;
        if (gidx < nChunk) {
          float4 v = logits4[(size_t)base * 10 + gidx];
          int row = gidx / 10, cc = gidx - row * 10;
          *(float4*)&sL[row * CEPAD + cc * 4] = v;
        }
      }
    }
    __syncthreads();
    if (t < tileN) {
      const float4* r = (const float4*)&sL[t * CEPAD];
      float x[40];
#pragma unroll
      for (int j = 0; j < 10; ++j) ((float4*)x)[j] = r[j];
      float L0 = 0.f, L1 = 0.f, L2 = 0.f, L3 = 0.f, L4 = 0.f;
#pragma unroll
      for (int mm = 0; mm < 8; ++mm) {
        L0 += x[mm * 5 + 0]; L1 += x[mm * 5 + 1]; L2 += x[mm * 5 + 2];
        L3 += x[mm * 5 + 3]; L4 += x[mm * 5 + 4];
      }
      L0 *= 0.125f; L1 *= 0.125f; L2 *= 0.125f; L3 *= 0.125f; L4 *= 0.125f;
      float mx = fmaxf(fmaxf(fmaxf(L0, L1), fmaxf(L2, L3)), L4);
      float se = __expf(L0 - mx) + __expf(L1 - mx) + __expf(L2 - mx) +
                 __expf(L3 - mx) + __expf(L4 - mx);
      float lse = __logf(se) + mx;
      int lb = lab[base + t];
      float lsel = (lb == 0) ? L0 : (lb == 1) ? L1 : (lb == 2) ? L2
                 : (lb == 3) ? L3 : L4;
      ce += lsel - lse;
    }
  }
  for (int o = 32; o; o >>= 1) ce += __shfl_down(ce, o);
  __shared__ float s_ce;
  if (t == 0) s_ce = 0.f;
  __syncthreads();
  if ((t & 63) == 0) atomicAdd(&s_ce, ce);
  __syncthreads();
  if (t == 0) unsafeAtomicAdd(&acc[8], (double)s_ce);
}

// Fold nparts padded partial histograms into one AoS histogram.
__global__ __launch_bounds__(256) void reduce_kernel(
    const float* __restrict__ partial, float* __restrict__ histAoS, int nparts)
{
  const int c  = blockIdx.x >> 6;
  const int bg = blockIdx.x & 63;
  const int tc = threadIdx.x & 31;
  const int tp = threadIdx.x >> 5;
  const int b = bg * 32 + tc;
  const int cell = c * NB2P + b;
  float s = 0.f;
  for (int p = tp; p < nparts; p += 8)
    s += partial[(size_t)p * NCELLP + cell];
  __shared__ float sh[256];
  sh[threadIdx.x] = s;
  __syncthreads();
  if (threadIdx.x < 32) {
    float v = 0.f;
#pragma unroll
    for (int k = 0; k < 8; ++k) v += sh[k * 32 + tc];
    histAoS[b * 4 + c] = v;
  }
}

// Inclusive suffix-sum over NB2 buckets (float4 = 4 causes). One WG.
__global__ __launch_bounds__(1024) void scan_kernel(
    const float* __restrict__ hist, float* __restrict__ suffix)
{
  const int CH = NB2 / 1024;   // 2
  const int t = threadIdx.x;
  __shared__ float4 part[1024];
  const float4* in = (const float4*)hist;
  float4* out = (float4*)suffix;

  float4 a = make_float4(0.f, 0.f, 0.f, 0.f);
  for (int j = 0; j < CH; ++j) {
    float4 v = in[t * CH + j];
    a.x += v.x; a.y += v.y; a.z += v.z; a.w += v.w;
  }
  part[t] = a;
  __syncthreads();
  for (int off = 1; off < 1024; off <<= 1) {
    float4 add = make_float4(0.f, 0.f, 0.f, 0.f);
    if (t + off < 1024) add = part[t + off];
    __syncthreads();
    float4 cur = part[t];
    cur.x += add.x; cur.y += add.y; cur.z += add.z; cur.w += add.w;
    part[t] = cur;
    __syncthreads();
  }
  float4 carry = (t < 1023) ? part[t + 1] : make_float4(0.f, 0.f, 0.f, 0.f);
  for (int j = CH - 1; j >= 0; --j) {
    float4 v = in[t * CH + j];
    carry.x += v.x; carry.y += v.y; carry.z += v.z; carry.w += v.w;
    out[t * CH + j] = carry;
  }
}

// ---- pass3: pure reduction (no fence/ticket — fused finalize cost 228us, R5) ----
__global__ __launch_bounds__(256) void pass3_kernel(
    const float* __restrict__ dur, const int* __restrict__ ev,
    const float* __restrict__ suffix, double* __restrict__ acc, int N)
{
  const int t = threadIdx.x;
  float lg0 = 0.f, lg1 = 0.f, lg2 = 0.f, lg3 = 0.f;
  const int i = blockIdx.x * 256 + t;
  if (i < N) {
    int e = ev[i];
    if (e > 0) {
      int b = (int)(dur[i] * (float)NB2);
      b = b < 0 ? 0 : (b > NB2 - 1 ? NB2 - 1 : b);
      float lv = __logf(suffix[(size_t)b * 4 + (e - 1)] + (float)EPS);
      lg0 = (e == 1) ? lv : 0.f;
      lg1 = (e == 2) ? lv : 0.f;
      lg2 = (e == 3) ? lv : 0.f;
      lg3 = (e == 4) ? lv : 0.f;
    }
  }
#define WRED(v) { for (int o = 32; o; o >>= 1) v += __shfl_down(v, o); }
  WRED(lg0) WRED(lg1) WRED(lg2) WRED(lg3)
  __shared__ float s_lg[4];
  if (t < 4) s_lg[t] = 0.f;
  __syncthreads();
  if ((t & 63) == 0) {
    atomicAdd(&s_lg[0], lg0); atomicAdd(&s_lg[1], lg1);
    atomicAdd(&s_lg[2], lg2); atomicAdd(&s_lg[3], lg3);
  }
  __syncthreads();
  if (t < 4 && s_lg[t] != 0.f) unsafeAtomicAdd(&acc[4 + t], (double)s_lg[t]);
}

__global__ void finalize_kernel(const double* __restrict__ acc,
                                const unsigned int* __restrict__ cnt,
                                float* __restrict__ out, int N)
{
  if (threadIdx.x == 0 && blockIdx.x == 0) {
    double ls = 0.0;
    for (int c = 0; c < 4; ++c) {
      double s = acc[c] - acc[4 + c];
      ls += -s / ((double)cnt[c] + EPS);
    }
    double ce = -acc[8] / (double)N;
    out[0] = (float)(ALPHA * ls + (1.0 - ALPHA) * ce);
  }
}

extern "C" void kernel_launch(void* const* d_in, const int* in_sizes, int n_in,
                              void* d_out, int out_size, void* d_ws, size_t ws_size,
                              hipStream_t stream) {
  const float4* log_h4  = (const float4*)d_in[0];
  const float4* logits4 = (const float4*)d_in[1];
  const float*  dur     = (const float*)d_in[2];
  const int*    ev      = (const int*)d_in[3];
  const int*    lab     = (const int*)d_in[4];
  const int N = in_sizes[2];

  const size_t partBytes = (size_t)NCELLP * sizeof(float);   // 32784 B
  const size_t histBytes = (size_t)NB2 * 4 * sizeof(float);  // 32 KB
  size_t fixed = 4096 + 2 * histBytes;
  int nparts = 1024;                     // 4 blocks/CU, 16 waves/CU (R4 config)
  if (ws_size > fixed) {
    size_t fit = (ws_size - fixed) / partBytes;
    if ((size_t)nparts > fit) nparts = (int)fit;
  }
  if (nparts < 1) nparts = 1;

  char* ws = (char*)d_ws;
  double* acc = (double*)ws;
  unsigned int* cnt = (unsigned int*)(ws + 128);
  float* partial = (float*)(ws + 4096);
  float* histAoS = (float*)(ws + 4096 + (size_t)nparts * partBytes);
  float* suffix  = (float*)(ws + 4096 + (size_t)nparts * partBytes + histBytes);

  hipMemsetAsync(ws, 0, 4096, stream);    // header only; all else fully written

  hazard_kernel<<<nparts, 256, 0, stream>>>(log_h4, dur, ev, partial, acc, cnt, N);
  ce_kernel<<<768, 256, 0, stream>>>(logits4, lab, acc, N);
  reduce_kernel<<<256, 256, 0, stream>>>(partial, histAoS, nparts);
  scan_kernel<<<1, 1024, 0, stream>>>(histAoS, suffix);
  const int nb = (N + 255) / 256;
  pass3_kernel<<<nb, 256, 0, stream>>>(dur, ev, suffix, acc, N);
  finalize_kernel<<<1, 1, 0, stream>>>(acc, cnt, (float*)d_out, N);
}